// Round 1
// baseline (92.208 us; speedup 1.0000x reference)
//
#include <hip/hip_runtime.h>

// Problem constants (fixed by setup_inputs)
constexpr int B     = 1000;
constexpr int T_PER = 250;
constexpr int M_PER = 50;
constexpr int N_T   = B * T_PER;   // 250000
constexpr int N_M   = B * M_PER;   // 50000
constexpr int H     = 128;
constexpr int N_LBL = 25000;
constexpr float EPS = 1e-05f;

constexpr int NB_T = 256;  // bn_stats blocks (tasks)
constexpr int NB_M = 64;   // bn_stats blocks (machines)
constexpr int NB_P = 64;   // prep blocks

// ---- ws layout ----
// fp32 region (float offsets)
constexpr int OFF_PART_T = 0;                       // 256 blocks * 32 (16 sum + 16 sq)
constexpr int OFF_PART_M = OFF_PART_T + NB_T * 32;  // 64 blocks * 16 (8 sum + 8 sq)
constexpr int OFF_MEANT  = OFF_PART_M + NB_M * 16;  // B*128
constexpr int OFF_MEANM  = OFF_MEANT + B * H;       // B*128
constexpr int OFF_HALF   = OFF_MEANM + B * H;       // fp16 region starts here (byte off 16-aligned)
// fp16 region (half offsets from wh)
constexpr int HO_WT1  = 0;       // 128*32
constexpr int HO_WT2  = 4096;    // 128*128
constexpr int HO_WM1  = 20480;   // 128*32
constexpr int HO_WM2  = 24576;   // 128*128
constexpr int HO_WA1  = 40960;   // 128*256
constexpr int HO_WA2  = 73728;   // 128*128
constexpr int HO_WL1  = 90112;   // 128*384
constexpr int HO_WL2  = 139264;  // 128*128
constexpr int HO_WO1  = 155648;  // 128*128 (end 172032)
constexpr int HO_XT16 = 172032;             // N_T*16 f16
constexpr int HO_XM16 = HO_XT16 + N_T * 16; // N_M*8 f16

typedef _Float16 f16x8 __attribute__((ext_vector_type(8)));
typedef _Float16 f16x4 __attribute__((ext_vector_type(4)));
typedef float f32x4 __attribute__((ext_vector_type(4)));

#define MFMA16(a, b, c) __builtin_amdgcn_mfma_f32_16x16x32_f16(a, b, c, 0, 0, 0)

// ---------------- K1: BN partial stats + x->f16 dump + weight transpose/convert ----------------
template <int C, int NB>
__device__ __forceinline__ void stats_body(const float* __restrict__ x,
                                           _Float16* __restrict__ x16, int nelem,
                                           float* __restrict__ part, int blk, int t,
                                           float* ls, float* lq) {
    float s = 0.f, q = 0.f;
    for (int e = blk * 256 + t; e < nelem; e += NB * 256) {
        float v = x[e];
        s += v;
        q += v * v;
        x16[e] = (_Float16)v;
    }
    ls[t] = s; lq[t] = q;
    __syncthreads();
    if (t < C) {
        float S = 0.f, Q = 0.f;
        for (int u = t; u < 256; u += C) { S += ls[u]; Q += lq[u]; }
        part[blk * 2 * C + t] = S;
        part[blk * 2 * C + C + t] = Q;
    }
}

__device__ __forceinline__ void cvt_tr(const float* __restrict__ src, _Float16* __restrict__ dst,
                                       int K, int Kp, int tid, int nt) {
    for (int idx = tid; idx < 128 * Kp; idx += nt) {
        int c = idx / Kp, k = idx - c * Kp;
        float v = (k < K) ? src[k * 128 + c] : 0.f;
        dst[idx] = (_Float16)v;
    }
}

__global__ __launch_bounds__(256) void stats_prep_kernel(
        const float* __restrict__ xt, const float* __restrict__ xm,
        _Float16* __restrict__ xt16, _Float16* __restrict__ xm16,
        const float* __restrict__ Wt1, const float* __restrict__ Wt2,
        const float* __restrict__ Wm1, const float* __restrict__ Wm2,
        const float* __restrict__ Wa1, const float* __restrict__ Wa2,
        const float* __restrict__ Wl1, const float* __restrict__ Wl2,
        const float* __restrict__ Wo1,
        float* __restrict__ wsf, _Float16* __restrict__ wh) {
    __shared__ float ls[256], lq[256];
    const int bid = blockIdx.x, t = threadIdx.x;
    if (bid < NB_T) {
        stats_body<16, NB_T>(xt, xt16, N_T * 16, wsf + OFF_PART_T, bid, t, ls, lq);
    } else if (bid < NB_T + NB_M) {
        stats_body<8, NB_M>(xm, xm16, N_M * 8, wsf + OFF_PART_M, bid - NB_T, t, ls, lq);
    } else {
        const int tid = (bid - NB_T - NB_M) * 256 + t;
        const int nt = NB_P * 256;
        cvt_tr(Wt1, wh + HO_WT1, 16, 32, tid, nt);
        cvt_tr(Wt2, wh + HO_WT2, 128, 128, tid, nt);
        cvt_tr(Wm1, wh + HO_WM1, 8, 32, tid, nt);
        cvt_tr(Wm2, wh + HO_WM2, 128, 128, tid, nt);
        cvt_tr(Wa1, wh + HO_WA1, 256, 256, tid, nt);
        cvt_tr(Wa2, wh + HO_WA2, 128, 128, tid, nt);
        cvt_tr(Wl1, wh + HO_WL1, 384, 384, tid, nt);
        cvt_tr(Wl2, wh + HO_WL2, 128, 128, tid, nt);
        cvt_tr(Wo1, wh + HO_WO1, 128, 128, tid, nt);
    }
}

// ---------------- column-split MFMA helpers ----------------
__device__ __forceinline__ void zacc(f32x4 acc[4][2]) {
#pragma unroll
    for (int rg = 0; rg < 4; rg++)
#pragma unroll
        for (int mi = 0; mi < 2; mi++) acc[rg][mi] = (f32x4){0.f, 0.f, 0.f, 0.f};
}

__device__ __forceinline__ void ld32(f16x8 w[2], const _Float16* __restrict__ WT,
                                     int m0, int r, int gq) {
#pragma unroll
    for (int mi = 0; mi < 2; mi++)
        w[mi] = *(const f16x8*)(WT + ((m0 + mi) * 16 + r) * 32 + gq * 8);
}

__device__ __forceinline__ void ld128(f16x8 w[2][4], const _Float16* __restrict__ WT,
                                      int lda, int k0, int m0, int r, int gq) {
#pragma unroll
    for (int mi = 0; mi < 2; mi++)
#pragma unroll
        for (int ks = 0; ks < 4; ks++)
            w[mi][ks] = *(const f16x8*)(WT + ((m0 + mi) * 16 + r) * lda + k0 + ks * 32 + gq * 8);
}

__device__ __forceinline__ void mm32(const f16x8 w[2], const _Float16* __restrict__ act,
                                     int rstride, int r, int gq, f32x4 acc[4][2]) {
#pragma unroll
    for (int rg = 0; rg < 4; rg++) {
        const f16x8 bf = *(const f16x8*)(act + (rg * 16 + r) * rstride + gq * 8);
        acc[rg][0] = MFMA16(w[0], bf, acc[rg][0]);
        acc[rg][1] = MFMA16(w[1], bf, acc[rg][1]);
    }
}

__device__ __forceinline__ void mm128(const f16x8 w[2][4], const _Float16* __restrict__ act,
                                      int rstride, int r, int gq, f32x4 acc[4][2]) {
#pragma unroll
    for (int rg = 0; rg < 4; rg++)
#pragma unroll
        for (int ks = 0; ks < 4; ks++) {
            const f16x8 bf = *(const f16x8*)(act + (rg * 16 + r) * rstride + ks * 32 + gq * 8);
            acc[rg][0] = MFMA16(w[0][ks], bf, acc[rg][0]);
            acc[rg][1] = MFMA16(w[1][ks], bf, acc[rg][1]);
        }
}

__device__ __forceinline__ void epi_cs(const f32x4 acc[4][2], const f32x4 bv[2],
                                       _Float16* __restrict__ dst, int dstride,
                                       int m0, int r, int gq, bool relu) {
#pragma unroll
    for (int rg = 0; rg < 4; rg++)
#pragma unroll
        for (int mi = 0; mi < 2; mi++) {
            f16x4 hv;
#pragma unroll
            for (int j = 0; j < 4; j++) {
                float v = acc[rg][mi][j] + bv[mi][j];
                if (relu) v = fmaxf(v, 0.f);
                hv[j] = (_Float16)v;
            }
            *(f16x4*)(dst + (rg * 16 + r) * dstride + (m0 + mi) * 16 + gq * 4) = hv;
        }
}

// ---------------- K2: fused per-segment 2-layer MLP + mean (per-block BN finalize) ----------------
template <int CIN, int ROWS, int PASSES, int NBS, int NTOT>
__device__ __forceinline__ void seg_body(
        const _Float16* __restrict__ x16, const float* __restrict__ pstats,
        const float* __restrict__ gamma, const float* __restrict__ beta,
        const float* __restrict__ W1f, const float* __restrict__ b1,
        const _Float16* __restrict__ W1T, const _Float16* __restrict__ W2T,
        const float* __restrict__ b2, float* __restrict__ meanout,
        int g, int t,
        _Float16* __restrict__ xs, _Float16* __restrict__ h1s,
        float* __restrict__ red, float* __restrict__ stat,
        float* __restrict__ sa, float* __restrict__ sb, float* __restrict__ b1f) {
    constexpr int S2 = 2 * CIN;
    constexpr int NCH = 256 / S2;
    // --- per-block BN finalize (partials are L2-hot: same 32KB for every block) ---
    {
        const int slot = t & (S2 - 1), chunk = t / S2;
        float s = 0.f;
        for (int b = chunk; b < NBS; b += NCH) s += pstats[b * S2 + slot];
        red[t] = s;
    }
    __syncthreads();
    if (t < S2) {
        float v = 0.f;
#pragma unroll
        for (int c = 0; c < NCH; c++) v += red[t + S2 * c];
        stat[t] = v;
    }
    __syncthreads();
    if (t < CIN) {
        float mu  = stat[t] * (1.f / (float)NTOT);
        float var = stat[CIN + t] * (1.f / (float)NTOT) - mu * mu;
        float a   = gamma[t] * rsqrtf(var + EPS);
        sa[t] = a;
        sb[t] = beta[t] - mu * a;
    }
    __syncthreads();
    if (t < 128) {
        float s = b1[t];
#pragma unroll
        for (int k = 0; k < CIN; k++) s += sb[k] * W1f[k * 128 + t];
        b1f[t] = s;
    }
    __syncthreads();

    const int lane = t & 63, wave = t >> 6;
    const int r = lane & 15, gq = lane >> 4;
    const int m0 = 2 * wave;
    f16x8 w1[2], w2[2][4];
    ld32(w1, W1T, m0, r, gq);
    if (gq * 8 < CIN) {  // fold BN scale into W1 fragment (a is per-K-column)
#pragma unroll
        for (int mi = 0; mi < 2; mi++)
#pragma unroll
            for (int e = 0; e < 8; e++)
                w1[mi][e] = (_Float16)((float)w1[mi][e] * sa[gq * 8 + e]);
    }
    ld128(w2, W2T, 128, 0, m0, r, gq);
    f32x4 b1v[2], b2v[2];
#pragma unroll
    for (int mi = 0; mi < 2; mi++) {
        b1v[mi] = *(const f32x4*)(b1f + (m0 + mi) * 16 + gq * 4);
        b2v[mi] = *(const f32x4*)(b2 + (m0 + mi) * 16 + gq * 4);
    }
    const int jrow = (CIN == 16) ? (t >> 2) : (t >> 1);
    const int prt  = (CIN == 16) ? (t & 3) : (t & 1);
    const bool stager = (CIN == 16) ? true : (t < 128);
    f16x4 z4; z4[0] = z4[1] = z4[2] = z4[3] = (_Float16)0.f;
    // zero K-pad cols CIN..31 once
    if (stager) {
        if (CIN == 16) {
            *(f16x4*)(xs + jrow * 40 + 16 + prt * 4) = z4;
        } else {
#pragma unroll
            for (int q = 0; q < 3; q++)
                *(f16x4*)(xs + jrow * 40 + 8 + prt * 12 + q * 4) = z4;
        }
    }
    f16x4 xr = z4;
    if (stager) {
        int cl = (jrow < ROWS) ? jrow : (ROWS - 1);
        xr = *(const f16x4*)(x16 + (g * ROWS + cl) * CIN + prt * 4);
    }
    f32x4 rs[2];
    rs[0] = (f32x4){0.f, 0.f, 0.f, 0.f};
    rs[1] = (f32x4){0.f, 0.f, 0.f, 0.f};
    for (int p = 0; p < PASSES; p++) {
        if (stager) {
            const bool valid = (p * 64 + jrow) < ROWS;
            f16x4 hv = valid ? xr : z4;
            *(f16x4*)(xs + jrow * 40 + prt * 4) = hv;
        }
        __syncthreads();
        if (p + 1 < PASSES && stager) {
            int lr = (p + 1) * 64 + jrow;
            int cl = (lr < ROWS) ? lr : (ROWS - 1);
            xr = *(const f16x4*)(x16 + (g * ROWS + cl) * CIN + prt * 4);
        }
        f32x4 acc[4][2];
        zacc(acc);
        mm32(w1, xs, 40, r, gq, acc);
        epi_cs(acc, b1v, h1s, 136, m0, r, gq, true);
        __syncthreads();
        zacc(acc);
        mm128(w2, h1s, 136, r, gq, acc);
        if ((p + 1) * 64 <= ROWS) {  // fully-valid pass: mask-free accumulate
#pragma unroll
            for (int rg = 0; rg < 4; rg++)
#pragma unroll
                for (int mi = 0; mi < 2; mi++)
#pragma unroll
                    for (int j = 0; j < 4; j++)
                        rs[mi][j] += fmaxf(acc[rg][mi][j] + b2v[mi][j], 0.f);
        } else {
#pragma unroll
            for (int rg = 0; rg < 4; rg++) {
                const float mk = ((p * 64 + rg * 16 + r) < ROWS) ? 1.f : 0.f;
#pragma unroll
                for (int mi = 0; mi < 2; mi++)
#pragma unroll
                    for (int j = 0; j < 4; j++)
                        rs[mi][j] = fmaf(fmaxf(acc[rg][mi][j] + b2v[mi][j], 0.f), mk, rs[mi][j]);
            }
        }
    }
#pragma unroll
    for (int mi = 0; mi < 2; mi++)
#pragma unroll
        for (int j = 0; j < 4; j++) {
            float v = rs[mi][j];
            v += __shfl_xor(v, 1); v += __shfl_xor(v, 2);
            v += __shfl_xor(v, 4); v += __shfl_xor(v, 8);
            rs[mi][j] = v;
        }
    if (r == 0) {
        constexpr float inv = 1.f / (float)ROWS;
#pragma unroll
        for (int mi = 0; mi < 2; mi++) {
            f32x4 st = rs[mi] * inv;
            *(f32x4*)(meanout + g * H + (m0 + mi) * 16 + gq * 4) = st;
        }
    }
}

__global__ __launch_bounds__(256) void seg_fused(
        const _Float16* __restrict__ xt16, const _Float16* __restrict__ xm16,
        const float* __restrict__ wsf,
        const float* __restrict__ gt, const float* __restrict__ btb,
        const float* __restrict__ gm, const float* __restrict__ bmb,
        const float* __restrict__ Wt1f, const float* __restrict__ bt1,
        const float* __restrict__ Wm1f, const float* __restrict__ bm1,
        const _Float16* __restrict__ wh,
        const float* __restrict__ bt2, const float* __restrict__ bm2,
        float* __restrict__ meanT, float* __restrict__ meanM) {
    __shared__ __attribute__((aligned(16))) _Float16 xs[64 * 40];
    __shared__ __attribute__((aligned(16))) _Float16 h1s[64 * 136];
    __shared__ float red[256], stat[32], sa[16], sb[16], b1f[128];
    if (blockIdx.x < B)
        seg_body<16, T_PER, 4, NB_T, N_T>(xt16, wsf + OFF_PART_T, gt, btb, Wt1f, bt1,
                                          wh + HO_WT1, wh + HO_WT2, bt2, meanT,
                                          blockIdx.x, threadIdx.x, xs, h1s, red, stat, sa, sb, b1f);
    else
        seg_body<8, M_PER, 1, NB_M, N_M>(xm16, wsf + OFF_PART_M, gm, bmb, Wm1f, bm1,
                                         wh + HO_WM1, wh + HO_WM2, bm2, meanM,
                                         blockIdx.x - B, threadIdx.x, xs, h1s, red, stat, sa, sb, b1f);
}

// ---------------- K3: label-row head (per-block BN finalize + per-block aggr recompute) ----------------
__global__ __launch_bounds__(256) void label_kernel(
        const float* __restrict__ xt,
        const _Float16* __restrict__ xt16, const _Float16* __restrict__ xm16,
        const float* __restrict__ wsf, const _Float16* __restrict__ wh,
        const float* __restrict__ gt, const float* __restrict__ btb,
        const float* __restrict__ gm, const float* __restrict__ bmb,
        const float* __restrict__ Wt1f, const float* __restrict__ bt1,
        const float* __restrict__ Wm1f, const float* __restrict__ bm1,
        const float* __restrict__ bt2, const float* __restrict__ bm2,
        const float* __restrict__ ba1, const float* __restrict__ ba2,
        const float* __restrict__ bl1, const float* __restrict__ bl2,
        const float* __restrict__ bo1,
        const float* __restrict__ Wo2, const float* __restrict__ bo2,
        const int* __restrict__ tbatch, const int* __restrict__ lidx,
        float* __restrict__ out) {
    __shared__ __attribute__((aligned(16))) _Float16 xs_t[64 * 40];
    __shared__ __attribute__((aligned(16))) _Float16 xs_m[64 * 40];
    __shared__ __attribute__((aligned(16))) _Float16 h1s[64 * 136];
    __shared__ __attribute__((aligned(16))) _Float16 cat[64 * 264];  // [th | mh]; aliased as cin/ags early
    __shared__ float psum[4][64];
    __shared__ int ridx[64], gidx[64], midx[64], slotS[64];
    __shared__ float red[256], statT[32], statM[16];
    __shared__ float saT[16], sbT[16], saM[8], sbM[8];
    __shared__ float b1ft[128], b1fm[128];
    __shared__ __attribute__((aligned(16))) float agg2s[16 * 132];

    const float* meanT = wsf + OFF_MEANT;
    const float* meanM = wsf + OFF_MEANM;
    const int t = threadIdx.x;
    const int lane = t & 63, wave = t >> 6;
    const int r = lane & 15, gq = lane >> 4;
    const int m0 = 2 * wave;

    // --- A: index gather ---
    if (t < 64) {
        int i = blockIdx.x * 64 + t;
        int rr = (i < N_LBL) ? lidx[i] : 0;
        ridx[t] = rr;
        int gg = tbatch[rr];
        gidx[t] = gg;
        float tv = xt[rr * 16 + 1];
        midx[t] = (tv == -1.0f) ? -1 : ((int)tv + gg * M_PER);
    }
    // --- B: BN finalize (tasks then machines) ---
    {
        const int slot = t & 31, chunk = t >> 5;
        const float* p = wsf + OFF_PART_T;
        float s = 0.f;
        for (int b = chunk; b < NB_T; b += 8) s += p[b * 32 + slot];
        red[t] = s;
    }
    __syncthreads();
    const int gbase = gidx[0];
    if (t < 32) {
        float v = 0.f;
#pragma unroll
        for (int c = 0; c < 8; c++) v += red[t + 32 * c];
        statT[t] = v;
    }
    if (t < 64) {
        int sl = gidx[t] - gbase;
        slotS[t] = (sl < 0) ? 0 : ((sl > 15) ? 15 : sl);
    }
    __syncthreads();
    {
        float s = 0.f;
        if (t < 128) {
            const int slot = t & 15, chunk = t >> 4;
            const float* p = wsf + OFF_PART_M;
            for (int b = chunk; b < NB_M; b += 8) s += p[b * 16 + slot];
        }
        red[t] = s;
    }
    __syncthreads();
    if (t < 16) {
        float v = 0.f;
#pragma unroll
        for (int c = 0; c < 8; c++) v += red[t + 16 * c];
        statM[t] = v;
    }
    __syncthreads();
    if (t < 16) {
        float mu  = statT[t] * (1.f / (float)N_T);
        float var = statT[16 + t] * (1.f / (float)N_T) - mu * mu;
        float a   = gt[t] * rsqrtf(var + EPS);
        saT[t] = a;
        sbT[t] = btb[t] - mu * a;
    } else if (t < 24) {
        int c = t - 16;
        float mu  = statM[c] * (1.f / (float)N_M);
        float var = statM[8 + c] * (1.f / (float)N_M) - mu * mu;
        float a   = gm[c] * rsqrtf(var + EPS);
        saM[c] = a;
        sbM[c] = bmb[c] - mu * a;
    }
    __syncthreads();
    if (t < 128) {
        float s = bt1[t];
#pragma unroll
        for (int k = 0; k < 16; k++) s += sbT[k] * Wt1f[k * 128 + t];
        b1ft[t] = s;
    } else {
        int c = t - 128;
        float s = bm1[c];
#pragma unroll
        for (int k = 0; k < 8; k++) s += sbM[k] * Wm1f[k * 128 + c];
        b1fm[c] = s;
    }
    __syncthreads();

    // --- C: stage label rows (raw f16, scale folded into W1) + cin for aggr ---
    f16x4 z4; z4[0] = z4[1] = z4[2] = z4[3] = (_Float16)0.f;
    {
        int j = t >> 2, prt = t & 3;
        f16x4 hv = *(const f16x4*)(xt16 + ridx[j] * 16 + prt * 4);
        *(f16x4*)(xs_t + j * 40 + prt * 4) = hv;
        *(f16x4*)(xs_t + j * 40 + 16 + prt * 4) = z4;
    }
    if (t < 128) {
        int j = t >> 1, prt = t & 1;
        int m = midx[j];
        f16x4 hv = z4;
        if (m >= 0) hv = *(const f16x4*)(xm16 + m * 8 + prt * 4);
        *(f16x4*)(xs_m + j * 40 + prt * 4) = hv;
#pragma unroll
        for (int q = 0; q < 3; q++)
            *(f16x4*)(xs_m + j * 40 + 8 + prt * 12 + q * 4) = z4;
    }
    _Float16* cin = cat;  // 16*264 in cat's low region
    for (int e = t; e < 16 * 64; e += 256) {
        int j = e >> 6, c4 = e & 63;
        int g = gbase + j;
        float4 v = {0.f, 0.f, 0.f, 0.f};
        if (g < B) v = (c4 < 32) ? *(const float4*)(meanT + g * H + c4 * 4)
                                 : *(const float4*)(meanM + g * H + (c4 - 32) * 4);
        f16x4 hv;
        hv[0] = (_Float16)v.x; hv[1] = (_Float16)v.y; hv[2] = (_Float16)v.z; hv[3] = (_Float16)v.w;
        *(f16x4*)(cin + j * 264 + c4 * 4) = hv;
    }
    // aggr weights (transient)
    f16x8 wa1[2][8], wa2[2][4], wl1b[2][4];
#pragma unroll
    for (int mi = 0; mi < 2; mi++)
#pragma unroll
        for (int ks = 0; ks < 8; ks++)
            wa1[mi][ks] = *(const f16x8*)(wh + HO_WA1 + ((m0 + mi) * 16 + r) * 256 + ks * 32 + gq * 8);
    ld128(wa2, wh + HO_WA2, 128, 0, m0, r, gq);
    ld128(wl1b, wh + HO_WL1, 384, 128, m0, r, gq);
    f32x4 bav[2], bbv[2], blv2[2];
#pragma unroll
    for (int mi = 0; mi < 2; mi++) {
        bav[mi]  = *(const f32x4*)(ba1 + (m0 + mi) * 16 + gq * 4);
        bbv[mi]  = *(const f32x4*)(ba2 + (m0 + mi) * 16 + gq * 4);
        blv2[mi] = *(const f32x4*)(bl1 + (m0 + mi) * 16 + gq * 4);
    }
    __syncthreads();
    // --- D: aggr MLP for the block's 16-graph window ---
    f32x4 a0 = {0.f, 0.f, 0.f, 0.f}, a1 = {0.f, 0.f, 0.f, 0.f};
    {
        const _Float16* bp = cin + r * 264 + gq * 8;
#pragma unroll
        for (int ks = 0; ks < 8; ks++) {
            const f16x8 bf = *(const f16x8*)(bp + ks * 32);
            a0 = MFMA16(wa1[0][ks], bf, a0);
            a1 = MFMA16(wa1[1][ks], bf, a1);
        }
    }
    {
        f16x4 h0, h1v;
#pragma unroll
        for (int j = 0; j < 4; j++) {
            h0[j]  = (_Float16)fmaxf(a0[j] + bav[0][j], 0.f);
            h1v[j] = (_Float16)fmaxf(a1[j] + bav[1][j], 0.f);
        }
        *(f16x4*)(h1s + r * 136 + m0 * 16 + gq * 4) = h0;
        *(f16x4*)(h1s + r * 136 + (m0 + 1) * 16 + gq * 4) = h1v;
    }
    __syncthreads();
    a0 = (f32x4){0.f, 0.f, 0.f, 0.f}; a1 = (f32x4){0.f, 0.f, 0.f, 0.f};
    {
        const _Float16* bp = h1s + r * 136 + gq * 8;
#pragma unroll
        for (int ks = 0; ks < 4; ks++) {
            const f16x8 bf = *(const f16x8*)(bp + ks * 32);
            a0 = MFMA16(wa2[0][ks], bf, a0);
            a1 = MFMA16(wa2[1][ks], bf, a1);
        }
    }
    {   // ags overwrites cin (cin's last read was before the prior barrier path: phase1 only)
        f16x4 h0, h1v;
#pragma unroll
        for (int j = 0; j < 4; j++) {
            h0[j]  = (_Float16)(a0[j] + bbv[0][j]);
            h1v[j] = (_Float16)(a1[j] + bbv[1][j]);
        }
        *(f16x4*)(cat + r * 136 + m0 * 16 + gq * 4) = h0;
        *(f16x4*)(cat + r * 136 + (m0 + 1) * 16 + gq * 4) = h1v;
    }
    __syncthreads();
    a0 = (f32x4){0.f, 0.f, 0.f, 0.f}; a1 = (f32x4){0.f, 0.f, 0.f, 0.f};
    {
        const _Float16* bp = cat + r * 136 + gq * 8;
#pragma unroll
        for (int ks = 0; ks < 4; ks++) {
            const f16x8 bf = *(const f16x8*)(bp + ks * 32);
            a0 = MFMA16(wl1b[0][ks], bf, a0);
            a1 = MFMA16(wl1b[1][ks], bf, a1);
        }
    }
    *(f32x4*)(agg2s + r * 132 + m0 * 16 + gq * 4) = a0 + blv2[0];
    *(f32x4*)(agg2s + r * 132 + (m0 + 1) * 16 + gq * 4) = a1 + blv2[1];
    __syncthreads();

    // --- E: main head pipeline ---
    f32x4 acc[4][2];
    // th
    f16x8 wt1[2]; ld32(wt1, wh + HO_WT1, m0, r, gq);
    if (gq < 2) {
#pragma unroll
        for (int mi = 0; mi < 2; mi++)
#pragma unroll
            for (int e = 0; e < 8; e++)
                wt1[mi][e] = (_Float16)((float)wt1[mi][e] * saT[gq * 8 + e]);
    }
    f16x8 wt2[2][4]; ld128(wt2, wh + HO_WT2, 128, 0, m0, r, gq);
    f32x4 bva[2], bvb[2];
#pragma unroll
    for (int mi = 0; mi < 2; mi++) {
        bva[mi] = *(const f32x4*)(b1ft + (m0 + mi) * 16 + gq * 4);
        bvb[mi] = *(const f32x4*)(bt2 + (m0 + mi) * 16 + gq * 4);
    }
    zacc(acc);
    mm32(wt1, xs_t, 40, r, gq, acc);
    epi_cs(acc, bva, h1s, 136, m0, r, gq, true);
    f16x8 wm1[2]; ld32(wm1, wh + HO_WM1, m0, r, gq);
    if (gq == 0) {
#pragma unroll
        for (int mi = 0; mi < 2; mi++)
#pragma unroll
            for (int e = 0; e < 8; e++)
                wm1[mi][e] = (_Float16)((float)wm1[mi][e] * saM[e]);
    }
    __syncthreads();
    zacc(acc);
    mm128(wt2, h1s, 136, r, gq, acc);
    epi_cs(acc, bvb, cat, 264, m0, r, gq, true);
    f16x8 wm2[2][4]; ld128(wm2, wh + HO_WM2, 128, 0, m0, r, gq);
    __syncthreads();
    // mh
#pragma unroll
    for (int mi = 0; mi < 2; mi++) {
        bva[mi] = *(const f32x4*)(b1fm + (m0 + mi) * 16 + gq * 4);
        bvb[mi] = *(const f32x4*)(bm2 + (m0 + mi) * 16 + gq * 4);
    }
    zacc(acc);
    mm32(wm1, xs_m, 40, r, gq, acc);
    epi_cs(acc, bva, h1s, 136, m0, r, gq, true);
    f16x8 wl1a[2][4]; ld128(wl1a, wh + HO_WL1, 384, 0, m0, r, gq);
    __syncthreads();
    zacc(acc);
    mm128(wm2, h1s, 136, r, gq, acc);
#pragma unroll
    for (int rg = 0; rg < 4; rg++) {
        const bool sent = (midx[rg * 16 + r] < 0);
#pragma unroll
        for (int mi = 0; mi < 2; mi++) {
            f16x4 hv;
#pragma unroll
            for (int j = 0; j < 4; j++) {
                float v = fmaxf(acc[rg][mi][j] + bvb[mi][j], 0.f);
                hv[j] = (_Float16)(sent ? 0.f : v);
            }
            *(f16x4*)(cat + (rg * 16 + r) * 264 + 128 + (m0 + mi) * 16 + gq * 4) = hv;
        }
    }
    f16x8 wl1c[2][4]; ld128(wl1c, wh + HO_WL1, 384, 256, m0, r, gq);
    __syncthreads();
    // head L1 (+agg2 from LDS)
    zacc(acc);
    mm128(wl1a, cat, 264, r, gq, acc);
    mm128(wl1c, cat + 128, 264, r, gq, acc);
#pragma unroll
    for (int rg = 0; rg < 4; rg++) {
        const int sl = slotS[rg * 16 + r];
#pragma unroll
        for (int mi = 0; mi < 2; mi++) {
            f32x4 av2 = *(const f32x4*)(agg2s + sl * 132 + (m0 + mi) * 16 + gq * 4);
            f16x4 hv;
#pragma unroll
            for (int j = 0; j < 4; j++)
                hv[j] = (_Float16)fmaxf(acc[rg][mi][j] + av2[j], 0.f);
            *(f16x4*)(h1s + (rg * 16 + r) * 136 + (m0 + mi) * 16 + gq * 4) = hv;
        }
    }
    f16x8 wl2[2][4]; ld128(wl2, wh + HO_WL2, 128, 0, m0, r, gq);
    __syncthreads();
    // head L2 (no relu)
#pragma unroll
    for (int mi = 0; mi < 2; mi++) bva[mi] = *(const f32x4*)(bl2 + (m0 + mi) * 16 + gq * 4);
    zacc(acc);
    mm128(wl2, h1s, 136, r, gq, acc);
    epi_cs(acc, bva, cat, 264, m0, r, gq, false);
    f16x8 wo1[2][4]; ld128(wo1, wh + HO_WO1, 128, 0, m0, r, gq);
    __syncthreads();
    // head L3 + dot Wo2
#pragma unroll
    for (int mi = 0; mi < 2; mi++) bva[mi] = *(const f32x4*)(bo1 + (m0 + mi) * 16 + gq * 4);
    f32x4 wo2v[2];
#pragma unroll
    for (int mi = 0; mi < 2; mi++) wo2v[mi] = *(const f32x4*)(Wo2 + (m0 + mi) * 16 + gq * 4);
    zacc(acc);
    mm128(wo1, cat, 264, r, gq, acc);
#pragma unroll
    for (int rg = 0; rg < 4; rg++) {
        float pv = 0.f;
#pragma unroll
        for (int mi = 0; mi < 2; mi++)
#pragma unroll
            for (int j = 0; j < 4; j++)
                pv += fmaxf(acc[rg][mi][j] + bva[mi][j], 0.f) * wo2v[mi][j];
        pv += __shfl_xor(pv, 16);
        pv += __shfl_xor(pv, 32);
        if (lane < 16) psum[wave][rg * 16 + lane] = pv;
    }
    __syncthreads();
    if (t < 64) {
        int i = blockIdx.x * 64 + t;
        if (i < N_LBL)
            out[i] = psum[0][t] + psum[1][t] + psum[2][t] + psum[3][t] + bo2[0];
    }
}

extern "C" void kernel_launch(void* const* d_in, const int* in_sizes, int n_in,
                              void* d_out, int out_size, void* d_ws, size_t ws_size,
                              hipStream_t stream) {
    const float* xt  = (const float*)d_in[0];
    const float* xm  = (const float*)d_in[1];
    const float* gt  = (const float*)d_in[2];
    const float* btb = (const float*)d_in[3];
    const float* Wt1 = (const float*)d_in[4];  const float* bt1 = (const float*)d_in[5];
    const float* Wt2 = (const float*)d_in[6];  const float* bt2 = (const float*)d_in[7];
    const float* gm  = (const float*)d_in[8];  const float* bmb = (const float*)d_in[9];
    const float* Wm1 = (const float*)d_in[10]; const float* bm1 = (const float*)d_in[11];
    const float* Wm2 = (const float*)d_in[12]; const float* bm2 = (const float*)d_in[13];
    const float* Wa1 = (const float*)d_in[14]; const float* ba1 = (const float*)d_in[15];
    const float* Wa2 = (const float*)d_in[16]; const float* ba2 = (const float*)d_in[17];
    const float* Wl1 = (const float*)d_in[18]; const float* bl1 = (const float*)d_in[19];
    const float* Wl2 = (const float*)d_in[20]; const float* bl2 = (const float*)d_in[21];
    const float* Wo1 = (const float*)d_in[22]; const float* bo1 = (const float*)d_in[23];
    const float* Wo2 = (const float*)d_in[24]; const float* bo2 = (const float*)d_in[25];
    const int* tb  = (const int*)d_in[26];
    const int* lix = (const int*)d_in[28];
    float* wsf = (float*)d_ws;
    _Float16* wh = (_Float16*)(wsf + OFF_HALF);
    _Float16* xt16 = wh + HO_XT16;
    _Float16* xm16 = wh + HO_XM16;
    float* outp = (float*)d_out;

    stats_prep_kernel<<<NB_T + NB_M + NB_P, 256, 0, stream>>>(
        xt, xm, xt16, xm16, Wt1, Wt2, Wm1, Wm2, Wa1, Wa2, Wl1, Wl2, Wo1, wsf, wh);
    seg_fused<<<2 * B, 256, 0, stream>>>(xt16, xm16, wsf,
                                         gt, btb, gm, bmb, Wt1, bt1, Wm1, bm1,
                                         wh, bt2, bm2,
                                         wsf + OFF_MEANT, wsf + OFF_MEANM);
    label_kernel<<<(N_LBL + 63) / 64, 256, 0, stream>>>(xt, xt16, xm16, wsf, wh,
                                                        gt, btb, gm, bmb,
                                                        Wt1, bt1, Wm1, bm1,
                                                        bt2, bm2, ba1, ba2, bl1, bl2, bo1,
                                                        Wo2, bo2, tb, lix, outp);
}

// Round 2
// 90.443 us; speedup vs baseline: 1.0195x; 1.0195x over previous
//
#include <hip/hip_runtime.h>

// Problem constants (fixed by setup_inputs)
constexpr int B     = 1000;
constexpr int T_PER = 250;
constexpr int M_PER = 50;
constexpr int N_T   = B * T_PER;   // 250000
constexpr int N_M   = B * M_PER;   // 50000
constexpr int H     = 128;
constexpr int N_LBL = 25000;
constexpr float EPS = 1e-05f;

constexpr int NB_T = 256;  // bn_stats blocks (tasks)
constexpr int NB_M = 64;   // bn_stats blocks (machines)
constexpr int NB_P = 64;   // prep blocks

// ---- ws layout ----
// fp32 region (float offsets)
constexpr int OFF_PART_T = 0;                       // 256 blocks * 32 (16 sum + 16 sq)
constexpr int OFF_PART_M = OFF_PART_T + NB_T * 32;  // 64 blocks * 16 (8 sum + 8 sq)
constexpr int OFF_AT     = OFF_PART_M + NB_M * 16;  // 16 task scale a
constexpr int OFF_BT     = OFF_AT + 16;             // 16 task shift b
constexpr int OFF_AM     = OFF_BT + 16;             // 8
constexpr int OFF_BM     = OFF_AM + 8;              // 8
constexpr int OFF_BT1F   = OFF_BM + 8;              // 128 folded bt1
constexpr int OFF_BM1F   = OFF_BT1F + 128;          // 128 folded bm1
constexpr int OFF_MEANT  = OFF_BM1F + 128;          // B*128 (task mean sums; agg2 overlay later)
constexpr int OFF_MEANM  = OFF_MEANT + B * H;       // B*128
constexpr int OFF_HALF   = OFF_MEANM + B * H;       // fp16 region starts here
// fp16 region (half offsets from wh)
constexpr int HO_WT1  = 0;       // 128*32
constexpr int HO_WT2  = 4096;    // 128*128
constexpr int HO_WM1  = 20480;   // 128*32
constexpr int HO_WM2  = 24576;   // 128*128
constexpr int HO_WA1  = 40960;   // 128*256
constexpr int HO_WA2  = 73728;   // 128*128
constexpr int HO_WL1  = 90112;   // 128*384
constexpr int HO_WL2  = 139264;  // 128*128
constexpr int HO_WO1  = 155648;  // 128*128 (end 172032)
constexpr int HO_XT16 = 172032;             // N_T*16 f16
constexpr int HO_XM16 = HO_XT16 + N_T * 16; // N_M*8 f16

typedef _Float16 f16x8 __attribute__((ext_vector_type(8)));
typedef _Float16 f16x4 __attribute__((ext_vector_type(4)));
typedef float f32x4 __attribute__((ext_vector_type(4)));

#define MFMA16(a, b, c) __builtin_amdgcn_mfma_f32_16x16x32_f16(a, b, c, 0, 0, 0)

// ---------------- K1: BN partial stats + x->f16 dump + weight transpose/convert + meanT zero ----------------
template <int C, int NB>
__device__ __forceinline__ void stats_body(const float* __restrict__ x,
                                           _Float16* __restrict__ x16, int nelem,
                                           float* __restrict__ part, int blk, int t,
                                           float* ls, float* lq) {
    float s = 0.f, q = 0.f;
    for (int e = blk * 256 + t; e < nelem; e += NB * 256) {
        float v = x[e];
        s += v;
        q += v * v;
        x16[e] = (_Float16)v;
    }
    ls[t] = s; lq[t] = q;
    __syncthreads();
    if (t < C) {
        float S = 0.f, Q = 0.f;
        for (int u = t; u < 256; u += C) { S += ls[u]; Q += lq[u]; }
        part[blk * 2 * C + t] = S;
        part[blk * 2 * C + C + t] = Q;
    }
}

__device__ __forceinline__ void cvt_tr(const float* __restrict__ src, _Float16* __restrict__ dst,
                                       int K, int Kp, int tid, int nt) {
    for (int idx = tid; idx < 128 * Kp; idx += nt) {
        int c = idx / Kp, k = idx - c * Kp;
        float v = (k < K) ? src[k * 128 + c] : 0.f;
        dst[idx] = (_Float16)v;
    }
}

__global__ __launch_bounds__(256) void stats_prep_kernel(
        const float* __restrict__ xt, const float* __restrict__ xm,
        _Float16* __restrict__ xt16, _Float16* __restrict__ xm16,
        const float* __restrict__ Wt1, const float* __restrict__ Wt2,
        const float* __restrict__ Wm1, const float* __restrict__ Wm2,
        const float* __restrict__ Wa1, const float* __restrict__ Wa2,
        const float* __restrict__ Wl1, const float* __restrict__ Wl2,
        const float* __restrict__ Wo1,
        float* __restrict__ wsf, _Float16* __restrict__ wh) {
    __shared__ float ls[256], lq[256];
    const int bid = blockIdx.x, t = threadIdx.x;
    if (bid < NB_T) {
        stats_body<16, NB_T>(xt, xt16, N_T * 16, wsf + OFF_PART_T, bid, t, ls, lq);
    } else if (bid < NB_T + NB_M) {
        stats_body<8, NB_M>(xm, xm16, N_M * 8, wsf + OFF_PART_M, bid - NB_T, t, ls, lq);
    } else {
        const int tid = (bid - NB_T - NB_M) * 256 + t;
        const int nt = NB_P * 256;
        // zero task-mean accumulators (atomicAdd targets in seg_fused)
        float* mz = wsf + OFF_MEANT;
        for (int i = tid; i < B * H; i += nt) mz[i] = 0.f;
        cvt_tr(Wt1, wh + HO_WT1, 16, 32, tid, nt);
        cvt_tr(Wt2, wh + HO_WT2, 128, 128, tid, nt);
        cvt_tr(Wm1, wh + HO_WM1, 8, 32, tid, nt);
        cvt_tr(Wm2, wh + HO_WM2, 128, 128, tid, nt);
        cvt_tr(Wa1, wh + HO_WA1, 256, 256, tid, nt);
        cvt_tr(Wa2, wh + HO_WA2, 128, 128, tid, nt);
        cvt_tr(Wl1, wh + HO_WL1, 384, 384, tid, nt);
        cvt_tr(Wl2, wh + HO_WL2, 128, 128, tid, nt);
        cvt_tr(Wo1, wh + HO_WO1, 128, 128, tid, nt);
    }
}

// ---------------- K2: BN finalize + bias folds (single block) ----------------
__global__ __launch_bounds__(256) void finalize_kernel(
        const float* __restrict__ gt, const float* __restrict__ btb,
        const float* __restrict__ gm, const float* __restrict__ bmb,
        const float* __restrict__ Wt1, const float* __restrict__ bt1,
        const float* __restrict__ Wm1, const float* __restrict__ bm1,
        float* __restrict__ ws) {
    __shared__ float red[256];
    __shared__ float statT[32], statM[16];
    __shared__ float shT[16], shM[8];
    const int t = threadIdx.x;
    // tasks: 32 slots x 256 blocks
    {
        const int slot = t & 31, chunk = t >> 5;
        const float* p = ws + OFF_PART_T;
        float s = 0.f;
        for (int b = chunk * 32; b < chunk * 32 + 32; b++) s += p[b * 32 + slot];
        red[t] = s;
    }
    __syncthreads();
    if (t < 32) {
        float v = 0.f;
#pragma unroll
        for (int c = 0; c < 8; c++) v += red[t + 32 * c];
        statT[t] = v;
    }
    __syncthreads();
    // machines: 16 slots x 64 blocks
    {
        float s = 0.f;
        if (t < 128) {
            const int slot = t & 15, chunk = t >> 4;
            const float* p = ws + OFF_PART_M;
            for (int b = chunk * 8; b < chunk * 8 + 8; b++) s += p[b * 16 + slot];
        }
        red[t] = s;
    }
    __syncthreads();
    if (t < 16) {
        float v = 0.f;
#pragma unroll
        for (int c = 0; c < 8; c++) v += red[t + 16 * c];
        statM[t] = v;
    }
    __syncthreads();
    if (t < 16) {
        float mu  = statT[t] / (float)N_T;
        float var = statT[16 + t] / (float)N_T - mu * mu;
        float a   = gt[t] * rsqrtf(var + EPS);
        ws[OFF_AT + t] = a;
        float b = btb[t] - mu * a;
        ws[OFF_BT + t] = b;
        shT[t] = b;
    } else if (t < 24) {
        int c = t - 16;
        float mu  = statM[c] / (float)N_M;
        float var = statM[8 + c] / (float)N_M - mu * mu;
        float a   = gm[c] * rsqrtf(var + EPS);
        ws[OFF_AM + c] = a;
        float b = bmb[c] - mu * a;
        ws[OFF_BM + c] = b;
        shM[c] = b;
    }
    __syncthreads();
    if (t < 128) {
        float s = bt1[t];
#pragma unroll
        for (int k = 0; k < 16; k++) s += shT[k] * Wt1[k * 128 + t];
        ws[OFF_BT1F + t] = s;
    } else {
        int c = t - 128;
        float s = bm1[c];
#pragma unroll
        for (int k = 0; k < 8; k++) s += shM[k] * Wm1[k * 128 + c];
        ws[OFF_BM1F + c] = s;
    }
}

// ---------------- column-split MFMA helpers ----------------
__device__ __forceinline__ void zacc(f32x4 acc[4][2]) {
#pragma unroll
    for (int rg = 0; rg < 4; rg++)
#pragma unroll
        for (int mi = 0; mi < 2; mi++) acc[rg][mi] = (f32x4){0.f, 0.f, 0.f, 0.f};
}

__device__ __forceinline__ void ld32(f16x8 w[2], const _Float16* __restrict__ WT,
                                     int m0, int r, int gq) {
#pragma unroll
    for (int mi = 0; mi < 2; mi++)
        w[mi] = *(const f16x8*)(WT + ((m0 + mi) * 16 + r) * 32 + gq * 8);
}

__device__ __forceinline__ void ld128(f16x8 w[2][4], const _Float16* __restrict__ WT,
                                      int lda, int k0, int m0, int r, int gq) {
#pragma unroll
    for (int mi = 0; mi < 2; mi++)
#pragma unroll
        for (int ks = 0; ks < 4; ks++)
            w[mi][ks] = *(const f16x8*)(WT + ((m0 + mi) * 16 + r) * lda + k0 + ks * 32 + gq * 8);
}

// GEMM1 with B-fragments held in registers (loaded straight from global)
__device__ __forceinline__ void mm32g(const f16x8 w[2], const f16x8 xb[4], f32x4 acc[4][2]) {
#pragma unroll
    for (int rg = 0; rg < 4; rg++) {
        acc[rg][0] = MFMA16(w[0], xb[rg], acc[rg][0]);
        acc[rg][1] = MFMA16(w[1], xb[rg], acc[rg][1]);
    }
}

__device__ __forceinline__ void mm128(const f16x8 w[2][4], const _Float16* __restrict__ act,
                                      int rstride, int r, int gq, f32x4 acc[4][2]) {
#pragma unroll
    for (int rg = 0; rg < 4; rg++)
#pragma unroll
        for (int ks = 0; ks < 4; ks++) {
            const f16x8 bf = *(const f16x8*)(act + (rg * 16 + r) * rstride + ks * 32 + gq * 8);
            acc[rg][0] = MFMA16(w[0][ks], bf, acc[rg][0]);
            acc[rg][1] = MFMA16(w[1][ks], bf, acc[rg][1]);
        }
}

__device__ __forceinline__ void epi_cs(const f32x4 acc[4][2], const f32x4 bv[2],
                                       _Float16* __restrict__ dst, int dstride,
                                       int m0, int r, int gq, bool relu) {
#pragma unroll
    for (int rg = 0; rg < 4; rg++)
#pragma unroll
        for (int mi = 0; mi < 2; mi++) {
            f16x4 hv;
#pragma unroll
            for (int j = 0; j < 4; j++) {
                float v = acc[rg][mi][j] + bv[mi][j];
                if (relu) v = fmaxf(v, 0.f);
                hv[j] = (_Float16)v;
            }
            *(f16x4*)(dst + (rg * 16 + r) * dstride + (m0 + mi) * 16 + gq * 4) = hv;
        }
}

// ---------------- K3: per-64-row-tile 2-layer MLP + (atomic) mean — ONE barrier per block ----------------
template <int CIN, int ROWS, bool ATOMIC>
__device__ __forceinline__ void seg_body(
        const _Float16* __restrict__ x16, const float* __restrict__ sa,
        const _Float16* __restrict__ W1T, const float* __restrict__ b1f,
        const _Float16* __restrict__ W2T, const float* __restrict__ b2,
        float* __restrict__ outp, int g, int r0, int t,
        _Float16* __restrict__ h1s) {
    const int lane = t & 63, wave = t >> 6;
    const int r = lane & 15, gq = lane >> 4;
    const int m0 = 2 * wave;
    f16x8 z8;
#pragma unroll
    for (int e = 0; e < 8; e++) z8[e] = (_Float16)0.f;
    // weight fragments (W2 issued early to hide L2 latency under GEMM1)
    f16x8 w1[2]; ld32(w1, W1T, m0, r, gq);
    f16x8 w2[2][4]; ld128(w2, W2T, 128, 0, m0, r, gq);
    if (gq * 8 < CIN) {  // fold BN scale into W1 fragment (scale is per-K-column)
        f32x4 s0 = *(const f32x4*)(sa + gq * 8);
        f32x4 s1 = *(const f32x4*)(sa + gq * 8 + 4);
#pragma unroll
        for (int mi = 0; mi < 2; mi++)
#pragma unroll
            for (int e = 0; e < 4; e++) {
                w1[mi][e]     = (_Float16)((float)w1[mi][e] * s0[e]);
                w1[mi][4 + e] = (_Float16)((float)w1[mi][4 + e] * s1[e]);
            }
    }
    // x B-fragments straight from global (row = lane&15, k = gq*8..+7)
    f16x8 xb[4];
#pragma unroll
    for (int rg = 0; rg < 4; rg++) {
        int row = r0 + rg * 16 + r;
        int cl = (row < ROWS) ? row : (ROWS - 1);
        if (CIN == 16) xb[rg] = (gq < 2) ? *(const f16x8*)(x16 + (g * ROWS + cl) * 16 + gq * 8) : z8;
        else           xb[rg] = (gq == 0) ? *(const f16x8*)(x16 + (g * ROWS + cl) * 8) : z8;
    }
    f32x4 b1v[2], b2v[2];
#pragma unroll
    for (int mi = 0; mi < 2; mi++) {
        b1v[mi] = *(const f32x4*)(b1f + (m0 + mi) * 16 + gq * 4);
        b2v[mi] = *(const f32x4*)(b2 + (m0 + mi) * 16 + gq * 4);
    }
    f32x4 acc[4][2];
    zacc(acc);
    mm32g(w1, xb, acc);
    epi_cs(acc, b1v, h1s, 136, m0, r, gq, true);
    __syncthreads();
    zacc(acc);
    mm128(w2, h1s, 136, r, gq, acc);
    f32x4 rs[2];
    rs[0] = (f32x4){0.f, 0.f, 0.f, 0.f};
    rs[1] = (f32x4){0.f, 0.f, 0.f, 0.f};
    if (r0 + 64 <= ROWS) {  // fully-valid tile: mask-free accumulate
#pragma unroll
        for (int rg = 0; rg < 4; rg++)
#pragma unroll
            for (int mi = 0; mi < 2; mi++)
#pragma unroll
                for (int j = 0; j < 4; j++)
                    rs[mi][j] += fmaxf(acc[rg][mi][j] + b2v[mi][j], 0.f);
    } else {
#pragma unroll
        for (int rg = 0; rg < 4; rg++) {
            const float mk = ((r0 + rg * 16 + r) < ROWS) ? 1.f : 0.f;
#pragma unroll
            for (int mi = 0; mi < 2; mi++)
#pragma unroll
                for (int j = 0; j < 4; j++)
                    rs[mi][j] = fmaf(fmaxf(acc[rg][mi][j] + b2v[mi][j], 0.f), mk, rs[mi][j]);
        }
    }
#pragma unroll
    for (int mi = 0; mi < 2; mi++)
#pragma unroll
        for (int j = 0; j < 4; j++) {
            float v = rs[mi][j];
            v += __shfl_xor(v, 1); v += __shfl_xor(v, 2);
            v += __shfl_xor(v, 4); v += __shfl_xor(v, 8);
            rs[mi][j] = v;
        }
    if (r == 0) {
        constexpr float inv = 1.f / (float)ROWS;
        if (ATOMIC) {
#pragma unroll
            for (int mi = 0; mi < 2; mi++)
#pragma unroll
                for (int j = 0; j < 4; j++)
                    atomicAdd(outp + g * H + (m0 + mi) * 16 + gq * 4 + j, rs[mi][j] * inv);
        } else {
#pragma unroll
            for (int mi = 0; mi < 2; mi++) {
                f32x4 st = rs[mi] * inv;
                *(f32x4*)(outp + g * H + (m0 + mi) * 16 + gq * 4) = st;
            }
        }
    }
}

__global__ __launch_bounds__(256) void seg_fused(
        const _Float16* __restrict__ xt16, const _Float16* __restrict__ xm16,
        const _Float16* __restrict__ wh, const float* __restrict__ wsf,
        const float* __restrict__ bt2, const float* __restrict__ bm2,
        float* __restrict__ meanT, float* __restrict__ meanM) {
    __shared__ __attribute__((aligned(16))) _Float16 h1s[64 * 136];
    const int bid = blockIdx.x;
    if (bid < 4 * B)
        seg_body<16, T_PER, true>(xt16, wsf + OFF_AT, wh + HO_WT1, wsf + OFF_BT1F,
                                  wh + HO_WT2, bt2, meanT, bid >> 2, (bid & 3) * 64,
                                  threadIdx.x, h1s);
    else
        seg_body<8, M_PER, false>(xm16, wsf + OFF_AM, wh + HO_WM1, wsf + OFF_BM1F,
                                  wh + HO_WM2, bm2, meanM, bid - 4 * B, 0,
                                  threadIdx.x, h1s);
}

// ---------------- K4: graph aggr MLP + fused aggr@Wl1b (16 graphs/block) ----------------
__global__ __launch_bounds__(256) void aggr_kernel(const float* __restrict__ meanT, const float* __restrict__ meanM,
        const _Float16* __restrict__ Wa1T, const float* __restrict__ ba1,
        const _Float16* __restrict__ Wa2T, const float* __restrict__ ba2,
        const _Float16* __restrict__ Wl1T, const float* __restrict__ bl1,
        float* __restrict__ agg2) {
    __shared__ __attribute__((aligned(16))) _Float16 cin[16 * 264];
    __shared__ __attribute__((aligned(16))) _Float16 h1s[16 * 136];
    __shared__ __attribute__((aligned(16))) _Float16 ags[16 * 136];
    const int t = threadIdx.x, lane = t & 63, wave = t >> 6;
    const int r = lane & 15, gq = lane >> 4;
    const int m0 = 2 * wave;
    const int g0 = blockIdx.x * 16;
    f16x8 wa1[2][8], wa2[2][4], wl1b[2][4];
#pragma unroll
    for (int mi = 0; mi < 2; mi++)
#pragma unroll
        for (int ks = 0; ks < 8; ks++)
            wa1[mi][ks] = *(const f16x8*)(Wa1T + ((m0 + mi) * 16 + r) * 256 + ks * 32 + gq * 8);
    ld128(wa2, Wa2T, 128, 0, m0, r, gq);
    ld128(wl1b, Wl1T, 384, 128, m0, r, gq);
    f32x4 b1v[2], b2v[2], blv[2];
#pragma unroll
    for (int mi = 0; mi < 2; mi++) {
        b1v[mi] = *(const f32x4*)(ba1 + (m0 + mi) * 16 + gq * 4);
        b2v[mi] = *(const f32x4*)(ba2 + (m0 + mi) * 16 + gq * 4);
        blv[mi] = *(const f32x4*)(bl1 + (m0 + mi) * 16 + gq * 4);
    }
    for (int e = t; e < 16 * 64; e += 256) {
        int j = e >> 6, c4 = e & 63;
        int g = g0 + j;
        float4 v = {0.f, 0.f, 0.f, 0.f};
        if (g < B) v = (c4 < 32) ? *(const float4*)(meanT + g * H + c4 * 4)
                                 : *(const float4*)(meanM + g * H + (c4 - 32) * 4);
        f16x4 hv;
        hv[0] = (_Float16)v.x; hv[1] = (_Float16)v.y; hv[2] = (_Float16)v.z; hv[3] = (_Float16)v.w;
        *(f16x4*)(cin + j * 264 + c4 * 4) = hv;
    }
    __syncthreads();
    f32x4 a0 = {0.f, 0.f, 0.f, 0.f}, a1 = {0.f, 0.f, 0.f, 0.f};
    {
        const _Float16* bp = cin + r * 264 + gq * 8;
#pragma unroll
        for (int ks = 0; ks < 8; ks++) {
            const f16x8 bf = *(const f16x8*)(bp + ks * 32);
            a0 = MFMA16(wa1[0][ks], bf, a0);
            a1 = MFMA16(wa1[1][ks], bf, a1);
        }
    }
    {
        f16x4 h0, h1v;
#pragma unroll
        for (int j = 0; j < 4; j++) {
            h0[j]  = (_Float16)fmaxf(a0[j] + b1v[0][j], 0.f);
            h1v[j] = (_Float16)fmaxf(a1[j] + b1v[1][j], 0.f);
        }
        *(f16x4*)(h1s + r * 136 + m0 * 16 + gq * 4) = h0;
        *(f16x4*)(h1s + r * 136 + (m0 + 1) * 16 + gq * 4) = h1v;
    }
    __syncthreads();
    a0 = (f32x4){0.f, 0.f, 0.f, 0.f}; a1 = (f32x4){0.f, 0.f, 0.f, 0.f};
    {
        const _Float16* bp = h1s + r * 136 + gq * 8;
#pragma unroll
        for (int ks = 0; ks < 4; ks++) {
            const f16x8 bf = *(const f16x8*)(bp + ks * 32);
            a0 = MFMA16(wa2[0][ks], bf, a0);
            a1 = MFMA16(wa2[1][ks], bf, a1);
        }
    }
    {
        f16x4 h0, h1v;
#pragma unroll
        for (int j = 0; j < 4; j++) {
            h0[j]  = (_Float16)(a0[j] + b2v[0][j]);
            h1v[j] = (_Float16)(a1[j] + b2v[1][j]);
        }
        *(f16x4*)(ags + r * 136 + m0 * 16 + gq * 4) = h0;
        *(f16x4*)(ags + r * 136 + (m0 + 1) * 16 + gq * 4) = h1v;
    }
    __syncthreads();
    a0 = (f32x4){0.f, 0.f, 0.f, 0.f}; a1 = (f32x4){0.f, 0.f, 0.f, 0.f};
    {
        const _Float16* bp = ags + r * 136 + gq * 8;
#pragma unroll
        for (int ks = 0; ks < 4; ks++) {
            const f16x8 bf = *(const f16x8*)(bp + ks * 32);
            a0 = MFMA16(wl1b[0][ks], bf, a0);
            a1 = MFMA16(wl1b[1][ks], bf, a1);
        }
    }
    // agg2 overlays meanT: barrier-separated read/write of the same 16 rows. Safe.
    if (g0 + r < B) {
        *(f32x4*)(agg2 + (g0 + r) * H + m0 * 16 + gq * 4) = a0 + blv[0];
        *(f32x4*)(agg2 + (g0 + r) * H + (m0 + 1) * 16 + gq * 4) = a1 + blv[1];
    }
}

// ---------------- K5: label-row head (direct-global B-frags, no xs LDS) ----------------
__global__ __launch_bounds__(256) void label_kernel(
        const float* __restrict__ xt,
        const _Float16* __restrict__ xt16, const _Float16* __restrict__ xm16,
        const float* __restrict__ scT, const float* __restrict__ scM,
        const _Float16* __restrict__ Wt1T, const float* __restrict__ bt1f,
        const _Float16* __restrict__ Wt2T, const float* __restrict__ bt2,
        const _Float16* __restrict__ Wm1T, const float* __restrict__ bm1f,
        const _Float16* __restrict__ Wm2T, const float* __restrict__ bm2,
        const _Float16* __restrict__ Wl1T,
        const _Float16* __restrict__ Wl2T, const float* __restrict__ bl2,
        const _Float16* __restrict__ Wo1T, const float* __restrict__ bo1,
        const float* __restrict__ Wo2, const float* __restrict__ bo2,
        const float* __restrict__ agg2,
        const int* __restrict__ tbatch, const int* __restrict__ lidx,
        float* __restrict__ out) {
    __shared__ __attribute__((aligned(16))) _Float16 h1s[64 * 136];
    __shared__ __attribute__((aligned(16))) _Float16 cat[64 * 264];  // [th | mh]
    __shared__ float psum[4][64];
    __shared__ int ridx[64], gidx[64], midx[64];
    const int t = threadIdx.x;
    const int lane = t & 63, wave = t >> 6;
    const int r = lane & 15, gq = lane >> 4;
    const int m0 = 2 * wave;
    if (t < 64) {
        int i = blockIdx.x * 64 + t;
        int rr = (i < N_LBL) ? lidx[i] : 0;
        ridx[t] = rr;
        int gg = tbatch[rr];
        gidx[t] = gg;
        float tv = xt[rr * 16 + 1];
        midx[t] = (tv == -1.0f) ? -1 : ((int)tv + gg * M_PER);
    }
    __syncthreads();
    f16x8 z8;
#pragma unroll
    for (int e = 0; e < 8; e++) z8[e] = (_Float16)0.f;
    // B-fragments for GEMM1s straight from global f16 x
    f16x8 xbT[4], xbM[4];
#pragma unroll
    for (int rg = 0; rg < 4; rg++) {
        int rr = ridx[rg * 16 + r];
        xbT[rg] = (gq < 2) ? *(const f16x8*)(xt16 + rr * 16 + gq * 8) : z8;
        int mm = midx[rg * 16 + r];
        xbM[rg] = (gq == 0 && mm >= 0) ? *(const f16x8*)(xm16 + mm * 8) : z8;
    }
    f32x4 agg2v[4][2];
#pragma unroll
    for (int rg = 0; rg < 4; rg++)
#pragma unroll
        for (int mi = 0; mi < 2; mi++)
            agg2v[rg][mi] = *(const f32x4*)(agg2 + gidx[rg * 16 + r] * H + (m0 + mi) * 16 + gq * 4);
    f32x4 acc[4][2];
    // --- th ---
    f16x8 wt1[2]; ld32(wt1, Wt1T, m0, r, gq);
    if (gq < 2) {  // fold BN scale into W1 fragment
        f32x4 s0 = *(const f32x4*)(scT + gq * 8);
        f32x4 s1 = *(const f32x4*)(scT + gq * 8 + 4);
#pragma unroll
        for (int mi = 0; mi < 2; mi++)
#pragma unroll
            for (int e = 0; e < 4; e++) {
                wt1[mi][e]     = (_Float16)((float)wt1[mi][e] * s0[e]);
                wt1[mi][4 + e] = (_Float16)((float)wt1[mi][4 + e] * s1[e]);
            }
    }
    f16x8 wt2[2][4]; ld128(wt2, Wt2T, 128, 0, m0, r, gq);
    f32x4 bva[2], bvb[2];
#pragma unroll
    for (int mi = 0; mi < 2; mi++) {
        bva[mi] = *(const f32x4*)(bt1f + (m0 + mi) * 16 + gq * 4);
        bvb[mi] = *(const f32x4*)(bt2 + (m0 + mi) * 16 + gq * 4);
    }
    zacc(acc);
    mm32g(wt1, xbT, acc);
    epi_cs(acc, bva, h1s, 136, m0, r, gq, true);
    f16x8 wm1[2]; ld32(wm1, Wm1T, m0, r, gq);
    if (gq == 0) {
        f32x4 s0 = *(const f32x4*)(scM);
        f32x4 s1 = *(const f32x4*)(scM + 4);
#pragma unroll
        for (int mi = 0; mi < 2; mi++)
#pragma unroll
            for (int e = 0; e < 4; e++) {
                wm1[mi][e]     = (_Float16)((float)wm1[mi][e] * s0[e]);
                wm1[mi][4 + e] = (_Float16)((float)wm1[mi][4 + e] * s1[e]);
            }
    }
    __syncthreads();
    zacc(acc);
    mm128(wt2, h1s, 136, r, gq, acc);
    epi_cs(acc, bvb, cat, 264, m0, r, gq, true);
    f16x8 wm2[2][4]; ld128(wm2, Wm2T, 128, 0, m0, r, gq);
    __syncthreads();
    // --- mh ---
#pragma unroll
    for (int mi = 0; mi < 2; mi++) {
        bva[mi] = *(const f32x4*)(bm1f + (m0 + mi) * 16 + gq * 4);
        bvb[mi] = *(const f32x4*)(bm2 + (m0 + mi) * 16 + gq * 4);
    }
    zacc(acc);
    mm32g(wm1, xbM, acc);
    epi_cs(acc, bva, h1s, 136, m0, r, gq, true);
    f16x8 wl1a[2][4]; ld128(wl1a, Wl1T, 384, 0, m0, r, gq);
    __syncthreads();
    zacc(acc);
    mm128(wm2, h1s, 136, r, gq, acc);
#pragma unroll
    for (int rg = 0; rg < 4; rg++) {
        const bool sent = (midx[rg * 16 + r] < 0);
#pragma unroll
        for (int mi = 0; mi < 2; mi++) {
            f16x4 hv;
#pragma unroll
            for (int j = 0; j < 4; j++) {
                float v = fmaxf(acc[rg][mi][j] + bvb[mi][j], 0.f);
                hv[j] = (_Float16)(sent ? 0.f : v);
            }
            *(f16x4*)(cat + (rg * 16 + r) * 264 + 128 + (m0 + mi) * 16 + gq * 4) = hv;
        }
    }
    f16x8 wl1c[2][4]; ld128(wl1c, Wl1T, 384, 256, m0, r, gq);
    __syncthreads();
    // --- head L1 ---
    zacc(acc);
    mm128(wl1a, cat, 264, r, gq, acc);
    mm128(wl1c, cat + 128, 264, r, gq, acc);
#pragma unroll
    for (int rg = 0; rg < 4; rg++)
#pragma unroll
        for (int mi = 0; mi < 2; mi++) {
            f16x4 hv;
#pragma unroll
            for (int j = 0; j < 4; j++)
                hv[j] = (_Float16)fmaxf(acc[rg][mi][j] + agg2v[rg][mi][j], 0.f);
            *(f16x4*)(h1s + (rg * 16 + r) * 136 + (m0 + mi) * 16 + gq * 4) = hv;
        }
    f16x8 wl2[2][4]; ld128(wl2, Wl2T, 128, 0, m0, r, gq);
    __syncthreads();
    // --- head L2 (no relu) ---
#pragma unroll
    for (int mi = 0; mi < 2; mi++) bva[mi] = *(const f32x4*)(bl2 + (m0 + mi) * 16 + gq * 4);
    zacc(acc);
    mm128(wl2, h1s, 136, r, gq, acc);
    epi_cs(acc, bva, cat, 264, m0, r, gq, false);
    f16x8 wo1[2][4]; ld128(wo1, Wo1T, 128, 0, m0, r, gq);
    __syncthreads();
    // --- head L3 + dot Wo2 ---
#pragma unroll
    for (int mi = 0; mi < 2; mi++) bva[mi] = *(const f32x4*)(bo1 + (m0 + mi) * 16 + gq * 4);
    f32x4 wo2v[2];
#pragma unroll
    for (int mi = 0; mi < 2; mi++) wo2v[mi] = *(const f32x4*)(Wo2 + (m0 + mi) * 16 + gq * 4);
    zacc(acc);
    mm128(wo1, cat, 264, r, gq, acc);
#pragma unroll
    for (int rg = 0; rg < 4; rg++) {
        float pv = 0.f;
#pragma unroll
        for (int mi = 0; mi < 2; mi++)
#pragma unroll
            for (int j = 0; j < 4; j++)
                pv += fmaxf(acc[rg][mi][j] + bva[mi][j], 0.f) * wo2v[mi][j];
        pv += __shfl_xor(pv, 16);
        pv += __shfl_xor(pv, 32);
        if (lane < 16) psum[wave][rg * 16 + lane] = pv;
    }
    __syncthreads();
    if (t < 64) {
        int i = blockIdx.x * 64 + t;
        if (i < N_LBL)
            out[i] = psum[0][t] + psum[1][t] + psum[2][t] + psum[3][t] + bo2[0];
    }
}

extern "C" void kernel_launch(void* const* d_in, const int* in_sizes, int n_in,
                              void* d_out, int out_size, void* d_ws, size_t ws_size,
                              hipStream_t stream) {
    const float* xt  = (const float*)d_in[0];
    const float* xm  = (const float*)d_in[1];
    const float* gt  = (const float*)d_in[2];
    const float* btb = (const float*)d_in[3];
    const float* Wt1 = (const float*)d_in[4];  const float* bt1 = (const float*)d_in[5];
    const float* Wt2 = (const float*)d_in[6];  const float* bt2 = (const float*)d_in[7];
    const float* gm  = (const float*)d_in[8];  const float* bmb = (const float*)d_in[9];
    const float* Wm1 = (const float*)d_in[10]; const float* bm1 = (const float*)d_in[11];
    const float* Wm2 = (const float*)d_in[12]; const float* bm2 = (const float*)d_in[13];
    const float* Wa1 = (const float*)d_in[14]; const float* ba1 = (const float*)d_in[15];
    const float* Wa2 = (const float*)d_in[16]; const float* ba2 = (const float*)d_in[17];
    const float* Wl1 = (const float*)d_in[18]; const float* bl1 = (const float*)d_in[19];
    const float* Wl2 = (const float*)d_in[20]; const float* bl2 = (const float*)d_in[21];
    const float* Wo1 = (const float*)d_in[22]; const float* bo1 = (const float*)d_in[23];
    const float* Wo2 = (const float*)d_in[24]; const float* bo2 = (const float*)d_in[25];
    const int* tb  = (const int*)d_in[26];
    const int* lix = (const int*)d_in[28];
    float* wsf = (float*)d_ws;
    _Float16* wh = (_Float16*)(wsf + OFF_HALF);
    _Float16* xt16 = wh + HO_XT16;
    _Float16* xm16 = wh + HO_XM16;
    float* outp = (float*)d_out;

    stats_prep_kernel<<<NB_T + NB_M + NB_P, 256, 0, stream>>>(
        xt, xm, xt16, xm16, Wt1, Wt2, Wm1, Wm2, Wa1, Wa2, Wl1, Wl2, Wo1, wsf, wh);
    finalize_kernel<<<1, 256, 0, stream>>>(gt, btb, gm, bmb, Wt1, bt1, Wm1, bm1, wsf);
    seg_fused<<<5 * B, 256, 0, stream>>>(xt16, xm16, wh, wsf, bt2, bm2,
                                         wsf + OFF_MEANT, wsf + OFF_MEANM);
    aggr_kernel<<<(B + 15) / 16, 256, 0, stream>>>(wsf + OFF_MEANT, wsf + OFF_MEANM,
                                                   wh + HO_WA1, ba1, wh + HO_WA2, ba2,
                                                   wh + HO_WL1, bl1, wsf + OFF_MEANT);
    label_kernel<<<(N_LBL + 63) / 64, 256, 0, stream>>>(xt, xt16, xm16,
                                                        wsf + OFF_AT, wsf + OFF_AM,
                                                        wh + HO_WT1, wsf + OFF_BT1F, wh + HO_WT2, bt2,
                                                        wh + HO_WM1, wsf + OFF_BM1F, wh + HO_WM2, bm2,
                                                        wh + HO_WL1,
                                                        wh + HO_WL2, bl2,
                                                        wh + HO_WO1, bo1, Wo2, bo2,
                                                        wsf + OFF_MEANT, tb, lix, outp);
}